// Round 2
// baseline (212.800 us; speedup 1.0000x reference)
//
#include <hip/hip_runtime.h>
#include <hip/hip_bf16.h>

#define NJ 24
#define NV 6890
#define NB 1024
#define V3 (NV*3)         // 20670 floats per batch in out
#define JTR_OFF (NB*NV*3)

typedef __attribute__((ext_vector_type(8))) short bf16x8;
typedef __attribute__((ext_vector_type(4))) float f32x4;

__constant__ int c_par[NJ] = {-1,0,0,0,1,2,3,4,5,6,7,8,9,9,9,12,13,14,16,17,18,19,20,21};

// ---------------------------------------------------------------------------
// k0: fold joint regressor: Jc[j][c][s], s<10: Jreg@shapedirs, s=10: Jreg@tmpl
// ---------------------------------------------------------------------------
__global__ void k0(const float* __restrict__ Jreg, const float* __restrict__ vtempl,
                   const float* __restrict__ shdirs, float* __restrict__ Jc)
{
    int j = blockIdx.x;
    float acc[33];
#pragma unroll
    for (int i = 0; i < 33; ++i) acc[i] = 0.0f;

    for (int v = blockIdx.y * 256 + threadIdx.x; v < NV; v += 1024) {
        float r = Jreg[j * NV + v];
#pragma unroll
        for (int c = 0; c < 3; ++c) {
            acc[c * 11 + 10] += r * vtempl[v * 3 + c];
            const float* sd = &shdirs[(v * 3 + c) * 10];
#pragma unroll
            for (int s = 0; s < 10; ++s) acc[c * 11 + s] += r * sd[s];
        }
    }
#pragma unroll
    for (int i = 0; i < 33; ++i) {
        float x = acc[i];
        for (int o = 32; o > 0; o >>= 1) x += __shfl_down(x, o, 64);
        acc[i] = x;
    }
    __shared__ float red[4][33];
    int w = threadIdx.x >> 6, l = threadIdx.x & 63;
    if (l == 0) {
#pragma unroll
        for (int i = 0; i < 33; ++i) red[w][i] = acc[i];
    }
    __syncthreads();
    if (threadIdx.x < 33) {
        float s = red[0][threadIdx.x] + red[1][threadIdx.x] +
                  red[2][threadIdx.x] + red[3][threadIdx.x];
        atomicAdd(&Jc[j * 33 + threadIdx.x], s);
    }
}

// ---------------------------------------------------------------------------
// kpack: build pdB_sw (bf16), pre-swizzled to the k2g LDS image order:
//   chunk cid = (((vtile*7 + kt)*3 + c)*4 + kq)*64 + v64 ; each chunk = 8 k.
// ---------------------------------------------------------------------------
__global__ void kpack(const float* __restrict__ pdirs, const float* __restrict__ shdirs,
                      const float* __restrict__ vtempl, __hip_bfloat16* __restrict__ pdBsw)
{
    int cid = blockIdx.x * 256 + threadIdx.x;   // < 580608
    int v64 = cid & 63;
    int t = cid >> 6;
    int kq = t & 3; t >>= 2;
    int c = t % 3; t /= 3;
    int kt = t % 7;
    int vt = t / 7;
    int v = vt * 64 + v64;

    ushort tmp[8] __attribute__((aligned(16)));
#pragma unroll
    for (int j = 0; j < 8; ++j) {
        int k = kt * 32 + kq * 8 + j;
        float val = 0.0f;
        if (v < NV) {
            if (k < 207)       val = pdirs[(v * 3 + c) * 207 + k];
            else if (k < 217)  val = shdirs[(v * 3 + c) * 10 + (k - 207)];
            else if (k == 217) val = vtempl[v * 3 + c];
        }
        __hip_bfloat16 h = __float2bfloat16(val);
        tmp[j] = *(ushort*)&h;
    }
    ((float4*)pdBsw)[cid] = *(const float4*)tmp;
}

// ---------------------------------------------------------------------------
// kwB: weights -> bf16 B-operand swizzle. chunk = (vtile*4 + kq)*64 + v64,
// 8 j each, K=32 (24 j + 8 zero pad).  27648 chunks.
// ---------------------------------------------------------------------------
__global__ void kwB(const float* __restrict__ wts, __hip_bfloat16* __restrict__ wtsB)
{
    int t = blockIdx.x * 256 + threadIdx.x;     // < 27648
    int v64 = t & 63;
    int kq = (t >> 6) & 3;
    int vt = t >> 8;
    int v = vt * 64 + v64;

    ushort tmp[8] __attribute__((aligned(16)));
#pragma unroll
    for (int j8 = 0; j8 < 8; ++j8) {
        int j = kq * 8 + j8;
        float val = (v < NV && j < NJ) ? wts[v * NJ + j] : 0.0f;
        __hip_bfloat16 h = __float2bfloat16(val);
        tmp[j8] = *(ushort*)&h;
    }
    ((float4*)wtsB)[t] = *(const float4*)tmp;
}

// ---------------------------------------------------------------------------
// k1: Rodrigues, A (bf16, swizzled), th_j, kinematic chain, G2B (bf16,
// A-operand swizzled, 12 components), th_jtr. One wave/batch, 4 batches/block.
// ABsw chunk: ((btile*7 + kt)*4 + kq)*64 + b64, 8 k each.
// G2B[mc] chunk: ((btile*4 + jq)*64 + b64)*8 + j7, mc stride 32768 elements.
// ---------------------------------------------------------------------------
__device__ __forceinline__ void writeA(__hip_bfloat16* ABsw, int b, int k, float val)
{
    int btile = b >> 6, b6 = b & 63, kt = k >> 5, kq = (k >> 3) & 3, j = k & 7;
    __hip_bfloat16 h = __float2bfloat16(val);
    ABsw[((((btile * 7) + kt) * 4 + kq) * 64 + b6) * 8 + j] = h;
}

__global__ void k1(const float* __restrict__ pose, const float* __restrict__ betas,
                   const float* __restrict__ trans, const float* __restrict__ Jc,
                   __hip_bfloat16* __restrict__ ABsw, __hip_bfloat16* __restrict__ G2B,
                   float* __restrict__ out)
{
    __shared__ float rots[4][NJ][9];
    __shared__ float thj [4][NJ][3];
    __shared__ float res [4][NJ][16];

    int w = threadIdx.x >> 6;
    int l = threadIdx.x & 63;
    int b = blockIdx.x * 4 + w;

    if (l < NJ) {
        int j = l;
        float ax = pose[b * 72 + j * 3 + 0];
        float ay = pose[b * 72 + j * 3 + 1];
        float az = pose[b * 72 + j * 3 + 2];
        float theta = sqrtf(ax * ax + ay * ay + az * az + 1e-8f);
        float inv = 1.0f / theta;
        float kx = ax * inv, ky = ay * inv, kz = az * inv;
        float c = cosf(theta), s = sinf(theta), mc = 1.0f - c;
        float R[9];
        R[0] = 1.0f - mc * (ky * ky + kz * kz);
        R[1] = -s * kz + mc * (kx * ky);
        R[2] =  s * ky + mc * (kx * kz);
        R[3] =  s * kz + mc * (kx * ky);
        R[4] = 1.0f - mc * (kx * kx + kz * kz);
        R[5] = -s * kx + mc * (ky * kz);
        R[6] = -s * ky + mc * (kx * kz);
        R[7] =  s * kx + mc * (ky * kz);
        R[8] = 1.0f - mc * (kx * kx + ky * ky);
#pragma unroll
        for (int e = 0; e < 9; ++e) rots[w][j][e] = R[e];
        if (j >= 1) {
            int base = (j - 1) * 9;
#pragma unroll
            for (int e = 0; e < 9; ++e) {
                float val = R[e] - ((e == 0 || e == 4 || e == 8) ? 1.0f : 0.0f);
                writeA(ABsw, b, base + e, val);
            }
        }
#pragma unroll
        for (int c3 = 0; c3 < 3; ++c3) {
            float acc = Jc[(j * 3 + c3) * 11 + 10];
#pragma unroll
            for (int s10 = 0; s10 < 10; ++s10)
                acc += Jc[(j * 3 + c3) * 11 + s10] * betas[b * 10 + s10];
            thj[w][j][c3] = acc;
        }
    } else if (l < 41) {
        int k = 207 + (l - 24);
        float val;
        if (l < 34)       val = betas[b * 10 + (l - 24)];
        else if (l == 34) val = 1.0f;
        else              val = 0.0f;
        writeA(ABsw, b, k, val);
    }
    __syncthreads();

    if (l < 16) {
        int m = l >> 2, n = l & 3;
        float v;
        if (m < 3) v = (n < 3) ? rots[w][0][m * 3 + n] : thj[w][0][m];
        else       v = (n == 3) ? 1.0f : 0.0f;
        res[w][0][l] = v;
    }
    __syncthreads();
#pragma unroll
    for (int i = 1; i < NJ; ++i) {
        int p = c_par[i];
        if (l < 16) {
            int m = l >> 2, n = l & 3;
            float acc = 0.0f;
#pragma unroll
            for (int k3 = 0; k3 < 3; ++k3) {
                float relkn = (n < 3) ? rots[w][i][k3 * 3 + n]
                                      : (thj[w][i][k3] - thj[w][p][k3]);
                acc += res[w][p][m * 4 + k3] * relkn;
            }
            if (n == 3) acc += res[w][p][m * 4 + 3];
            res[w][i][l] = acc;
        }
        __syncthreads();
    }

    if (l < NJ) {
        int j = l;
#pragma unroll
        for (int c3 = 0; c3 < 3; ++c3)
            out[JTR_OFF + b * 72 + j * 3 + c3] = res[w][j][c3 * 4 + 3] + trans[b * 3 + c3];
    }
    // G2B: 12 components mc = m*4+n, K=32 (j=24..31 zero), bf16 A-operand swizzle
    for (int k = l; k < 384; k += 64) {
        int mc = k >> 5, j = k & 31;
        int m = mc >> 2, n = mc & 3;
        float v = 0.0f;
        if (j < NJ) {
            if (n < 3) v = res[w][j][m * 4 + n];
            else v = res[w][j][m * 4 + 3] - (res[w][j][m * 4 + 0] * thj[w][j][0] +
                                             res[w][j][m * 4 + 1] * thj[w][j][1] +
                                             res[w][j][m * 4 + 2] * thj[w][j][2]);
        }
        __hip_bfloat16 h = __float2bfloat16(v);
        G2B[mc * 32768 + ((((b >> 6) * 4) + (j >> 3)) * 64 + (b & 63)) * 8 + (j & 7)] = h;
    }
}

// ---------------------------------------------------------------------------
// k2g: fused pose-GEMM + MFMA blend.  A = batches (M), B = verts (N).
// Block: 64b x 64v x 3c, 4 waves (2x2), K-loop 7 x 32, mfma 16x16x32 bf16.
// v3: T14 async-STAGE split — kt+1's global loads are issued right after the
// pre-MFMA barrier and held in registers; the ds_write (and its vmcnt wait)
// happens at the top of the next iteration, so HBM/L2 latency hides under
// the 12-MFMA phase instead of sitting on the critical path every kt.
// Also __launch_bounds__(256,4): was (256,3)/35% occupancy — latency-bound
// (53 us for 115 MB = 2.2 TB/s effective); 4 blocks/CU adds TLP for the
// epilogue's 24 scattered L2-hit G2B loads and the store drain.
// Epilogue gathers xyz in regs, one contiguous 12 B store per (b,v) (the
// m-outermost ordering previously caused 3.1x HBM write amplification).
// ---------------------------------------------------------------------------
__launch_bounds__(256, 4)
__global__ void k2g(const __hip_bfloat16* __restrict__ pdBsw,
                    const __hip_bfloat16* __restrict__ ABsw,
                    const __hip_bfloat16* __restrict__ G2B,
                    const __hip_bfloat16* __restrict__ wtsB,
                    const float* __restrict__ trans,
                    float* __restrict__ outp)
{
    __shared__ ushort As[3 * 4 * 64 * 8] __attribute__((aligned(16)));  // verts, 12 KB
    __shared__ ushort Bs[4 * 64 * 8]     __attribute__((aligned(16)));  // batch, 4 KB

    int tid = threadIdx.x;
    int vtile = blockIdx.x;      // 0..107
    int btile = blockIdx.y;      // 0..15
    int wid = tid >> 6, lane = tid & 63;
    int waveb = wid & 1, wavev = wid >> 1;
    int kq = lane >> 4, l15 = lane & 15;

    const float4* pA4 = (const float4*)pdBsw;
    const float4* pB4 = (const float4*)ABsw;

    f32x4 acc[3][2][2] = {};   // [c][mi=b-sub][ni=v-sub]

    int aoff = (kq * 64 + waveb * 32 + l15) * 8;      // batch frag (from Bs) + mi*128
    int boff = (kq * 64 + wavev * 32 + l15) * 8;      // vert frag (from As) + ni*128 + c*2048

    // prologue: stage kt=0 into registers
    float4 ra0, ra1, ra2, rb0;
    {
        int abase = (vtile * 7) * 768;
        int bbase = (btile * 7) * 256;
        ra0 = pA4[abase + tid];
        ra1 = pA4[abase + tid + 256];
        ra2 = pA4[abase + tid + 512];
        rb0 = pB4[bbase + tid];
    }

    for (int kt = 0; kt < 7; ++kt) {
        ((float4*)As)[tid]       = ra0;
        ((float4*)As)[tid + 256] = ra1;
        ((float4*)As)[tid + 512] = ra2;
        ((float4*)Bs)[tid]       = rb0;
        __syncthreads();

        // issue next tile's loads NOW — latency hides under the MFMA phase
        if (kt < 6) {
            int abase = (vtile * 7 + kt + 1) * 768;
            int bbase = (btile * 7 + kt + 1) * 256;
            ra0 = pA4[abase + tid];
            ra1 = pA4[abase + tid + 256];
            ra2 = pA4[abase + tid + 512];
            rb0 = pB4[bbase + tid];
        }

        bf16x8 af[2];
#pragma unroll
        for (int mi = 0; mi < 2; ++mi)
            af[mi] = *(const bf16x8*)&Bs[aoff + mi * 128];
#pragma unroll
        for (int c = 0; c < 3; ++c) {
            bf16x8 bfr[2];
#pragma unroll
            for (int ni = 0; ni < 2; ++ni)
                bfr[ni] = *(const bf16x8*)&As[boff + c * 2048 + ni * 128];
#pragma unroll
            for (int mi = 0; mi < 2; ++mi)
#pragma unroll
                for (int ni = 0; ni < 2; ++ni)
                    acc[c][mi][ni] = __builtin_amdgcn_mfma_f32_16x16x32_bf16(
                        af[mi], bfr[ni], acc[c][mi][ni], 0, 0, 0);
        }
        __syncthreads();
    }

    // ---- blend epilogue ----
    // wts B-frags (col = v), one per ni — same for all 12 components
    bf16x8 wf[2];
#pragma unroll
    for (int ni = 0; ni < 2; ++ni)
        wf[ni] = *(const bf16x8*)&wtsB[(((vtile * 4 + kq) * 64) +
                                        wavev * 32 + ni * 16 + l15) * 8];

    int bframe = ((btile * 4 + kq) * 64 + waveb * 32 + l15) * 8;  // + mi*128

#pragma unroll
    for (int mi = 0; mi < 2; ++mi) {
        float res3[2][4][3];   // [ni][r][m] — xyz gathered before store
#pragma unroll
        for (int m = 0; m < 3; ++m) {
            f32x4 T[4][2] = {};
#pragma unroll
            for (int c4 = 0; c4 < 4; ++c4) {
                int mc = m * 4 + c4;
                bf16x8 gf = *(const bf16x8*)&G2B[mc * 32768 + bframe + mi * 128];
#pragma unroll
                for (int ni = 0; ni < 2; ++ni)
                    T[c4][ni] = __builtin_amdgcn_mfma_f32_16x16x32_bf16(
                        gf, wf[ni], T[c4][ni], 0, 0, 0);
            }
#pragma unroll
            for (int ni = 0; ni < 2; ++ni) {
#pragma unroll
                for (int r = 0; r < 4; ++r) {
                    float x = acc[0][mi][ni][r];
                    float y = acc[1][mi][ni][r];
                    float z = acc[2][mi][ni][r];
                    res3[ni][r][m] = T[3][ni][r] + T[0][ni][r] * x +
                                     T[1][ni][r] * y + T[2][ni][r] * z;
                }
            }
        }
        // dense stores: one contiguous 12 B (x,y,z) per (b,v)
#pragma unroll
        for (int ni = 0; ni < 2; ++ni) {
            int v = vtile * 64 + wavev * 32 + ni * 16 + l15;
            if (v < NV) {
#pragma unroll
                for (int r = 0; r < 4; ++r) {
                    int b = btile * 64 + waveb * 32 + mi * 16 + (kq << 2) + r;
                    float* dst = &outp[(size_t)b * V3 + v * 3];
                    dst[0] = res3[ni][r][0] + trans[b * 3 + 0];
                    dst[1] = res3[ni][r][1] + trans[b * 3 + 1];
                    dst[2] = res3[ni][r][2] + trans[b * 3 + 2];
                }
            }
        }
    }
}

extern "C" void kernel_launch(void* const* d_in, const int* in_sizes, int n_in,
                              void* d_out, int out_size, void* d_ws, size_t ws_size,
                              hipStream_t stream)
{
    const float* pose   = (const float*)d_in[0];
    const float* betas  = (const float*)d_in[1];
    const float* trans  = (const float*)d_in[2];
    const float* vtempl = (const float*)d_in[3];
    const float* shdirs = (const float*)d_in[4];
    const float* pdirs  = (const float*)d_in[5];
    const float* Jreg   = (const float*)d_in[6];
    const float* wts    = (const float*)d_in[7];
    float* out = (float*)d_out;
    char* ws = (char*)d_ws;

    float* Jc              = (float*)(ws);                      // 792 fl (4 KB)
    __hip_bfloat16* ABsw   = (__hip_bfloat16*)(ws + 4096);      // 229376 bf16
    __hip_bfloat16* G2B    = (__hip_bfloat16*)(ws + 462848);    // 393216 bf16
    __hip_bfloat16* wtsB   = (__hip_bfloat16*)(ws + 1249280);   // 221184 bf16
    __hip_bfloat16* pdBsw  = (__hip_bfloat16*)(ws + 1691648);   // 4644864 bf16

    hipMemsetAsync(Jc, 0, NJ * 33 * sizeof(float), stream);
    hipLaunchKernelGGL(k0, dim3(NJ, 4), dim3(256), 0, stream, Jreg, vtempl, shdirs, Jc);
    hipLaunchKernelGGL(kpack, dim3(2268), dim3(256), 0, stream, pdirs, shdirs, vtempl, pdBsw);
    hipLaunchKernelGGL(kwB, dim3(108), dim3(256), 0, stream, wts, wtsB);
    hipLaunchKernelGGL(k1, dim3(NB / 4), dim3(256), 0, stream,
                       pose, betas, trans, Jc, ABsw, G2B, out);
    hipLaunchKernelGGL(k2g, dim3(108, 16), dim3(256), 0, stream,
                       pdBsw, ABsw, G2B, wtsB, trans, out);
}

// Round 4
// 192.686 us; speedup vs baseline: 1.1044x; 1.1044x over previous
//
#include <hip/hip_runtime.h>
#include <hip/hip_bf16.h>

#define NJ 24
#define NV 6890
#define NB 1024
#define V3 (NV*3)         // 20670 floats per batch in out
#define JTR_OFF (NB*NV*3)

typedef __attribute__((ext_vector_type(8))) short bf16x8;
typedef __attribute__((ext_vector_type(4))) float f32x4;
typedef float f4u __attribute__((ext_vector_type(4), aligned(4)));

__constant__ int c_par[NJ] = {-1,0,0,0,1,2,3,4,5,6,7,8,9,9,9,12,13,14,16,17,18,19,20,21};

// ---------------------------------------------------------------------------
// k0: fold joint regressor: Jc[j][c][s], s<10: Jreg@shapedirs, s=10: Jreg@tmpl
// ---------------------------------------------------------------------------
__global__ void k0(const float* __restrict__ Jreg, const float* __restrict__ vtempl,
                   const float* __restrict__ shdirs, float* __restrict__ Jc)
{
    int j = blockIdx.x;
    float acc[33];
#pragma unroll
    for (int i = 0; i < 33; ++i) acc[i] = 0.0f;

    for (int v = blockIdx.y * 256 + threadIdx.x; v < NV; v += 1024) {
        float r = Jreg[j * NV + v];
#pragma unroll
        for (int c = 0; c < 3; ++c) {
            acc[c * 11 + 10] += r * vtempl[v * 3 + c];
            const float* sd = &shdirs[(v * 3 + c) * 10];
#pragma unroll
            for (int s = 0; s < 10; ++s) acc[c * 11 + s] += r * sd[s];
        }
    }
#pragma unroll
    for (int i = 0; i < 33; ++i) {
        float x = acc[i];
        for (int o = 32; o > 0; o >>= 1) x += __shfl_down(x, o, 64);
        acc[i] = x;
    }
    __shared__ float red[4][33];
    int w = threadIdx.x >> 6, l = threadIdx.x & 63;
    if (l == 0) {
#pragma unroll
        for (int i = 0; i < 33; ++i) red[w][i] = acc[i];
    }
    __syncthreads();
    if (threadIdx.x < 33) {
        float s = red[0][threadIdx.x] + red[1][threadIdx.x] +
                  red[2][threadIdx.x] + red[3][threadIdx.x];
        atomicAdd(&Jc[j * 33 + threadIdx.x], s);
    }
}

// ---------------------------------------------------------------------------
// kpack: build pdB_sw (bf16), pre-swizzled to the k2g LDS image order:
//   chunk cid = (((vtile*7 + kt)*3 + c)*4 + kq)*64 + v64 ; each chunk = 8 k.
// ---------------------------------------------------------------------------
__global__ void kpack(const float* __restrict__ pdirs, const float* __restrict__ shdirs,
                      const float* __restrict__ vtempl, __hip_bfloat16* __restrict__ pdBsw)
{
    int cid = blockIdx.x * 256 + threadIdx.x;   // < 580608
    int v64 = cid & 63;
    int t = cid >> 6;
    int kq = t & 3; t >>= 2;
    int c = t % 3; t /= 3;
    int kt = t % 7;
    int vt = t / 7;
    int v = vt * 64 + v64;

    ushort tmp[8] __attribute__((aligned(16)));
#pragma unroll
    for (int j = 0; j < 8; ++j) {
        int k = kt * 32 + kq * 8 + j;
        float val = 0.0f;
        if (v < NV) {
            if (k < 207)       val = pdirs[(v * 3 + c) * 207 + k];
            else if (k < 217)  val = shdirs[(v * 3 + c) * 10 + (k - 207)];
            else if (k == 217) val = vtempl[v * 3 + c];
        }
        __hip_bfloat16 h = __float2bfloat16(val);
        tmp[j] = *(ushort*)&h;
    }
    ((float4*)pdBsw)[cid] = *(const float4*)tmp;
}

// ---------------------------------------------------------------------------
// kwB: weights -> bf16 B-operand swizzle. chunk = (vtile*4 + kq)*64 + v64,
// 8 j each, K=32 (24 j + 8 zero pad).  27648 chunks.
// ---------------------------------------------------------------------------
__global__ void kwB(const float* __restrict__ wts, __hip_bfloat16* __restrict__ wtsB)
{
    int t = blockIdx.x * 256 + threadIdx.x;     // < 27648
    int v64 = t & 63;
    int kq = (t >> 6) & 3;
    int vt = t >> 8;
    int v = vt * 64 + v64;

    ushort tmp[8] __attribute__((aligned(16)));
#pragma unroll
    for (int j8 = 0; j8 < 8; ++j8) {
        int j = kq * 8 + j8;
        float val = (v < NV && j < NJ) ? wts[v * NJ + j] : 0.0f;
        __hip_bfloat16 h = __float2bfloat16(val);
        tmp[j8] = *(ushort*)&h;
    }
    ((float4*)wtsB)[t] = *(const float4*)tmp;
}

// ---------------------------------------------------------------------------
// k1: Rodrigues, A (bf16, swizzled), th_j, kinematic chain, G2B (bf16,
// A-operand swizzled, 12 components), th_jtr. One wave/batch, 4 batches/block.
// ABsw chunk: ((btile*7 + kt)*4 + kq)*64 + b64, 8 k each.
// G2B[mc] chunk: ((btile*4 + jq)*64 + b64)*8 + j7, mc stride 32768 elements.
// ---------------------------------------------------------------------------
__device__ __forceinline__ void writeA(__hip_bfloat16* ABsw, int b, int k, float val)
{
    int btile = b >> 6, b6 = b & 63, kt = k >> 5, kq = (k >> 3) & 3, j = k & 7;
    __hip_bfloat16 h = __float2bfloat16(val);
    ABsw[((((btile * 7) + kt) * 4 + kq) * 64 + b6) * 8 + j] = h;
}

__global__ void k1(const float* __restrict__ pose, const float* __restrict__ betas,
                   const float* __restrict__ trans, const float* __restrict__ Jc,
                   __hip_bfloat16* __restrict__ ABsw, __hip_bfloat16* __restrict__ G2B,
                   float* __restrict__ out)
{
    __shared__ float rots[4][NJ][9];
    __shared__ float thj [4][NJ][3];
    __shared__ float res [4][NJ][16];

    int w = threadIdx.x >> 6;
    int l = threadIdx.x & 63;
    int b = blockIdx.x * 4 + w;

    if (l < NJ) {
        int j = l;
        float ax = pose[b * 72 + j * 3 + 0];
        float ay = pose[b * 72 + j * 3 + 1];
        float az = pose[b * 72 + j * 3 + 2];
        float theta = sqrtf(ax * ax + ay * ay + az * az + 1e-8f);
        float inv = 1.0f / theta;
        float kx = ax * inv, ky = ay * inv, kz = az * inv;
        float c = cosf(theta), s = sinf(theta), mc = 1.0f - c;
        float R[9];
        R[0] = 1.0f - mc * (ky * ky + kz * kz);
        R[1] = -s * kz + mc * (kx * ky);
        R[2] =  s * ky + mc * (kx * kz);
        R[3] =  s * kz + mc * (kx * ky);
        R[4] = 1.0f - mc * (kx * kx + kz * kz);
        R[5] = -s * kx + mc * (ky * kz);
        R[6] = -s * ky + mc * (kx * kz);
        R[7] =  s * kx + mc * (ky * kz);
        R[8] = 1.0f - mc * (kx * kx + ky * ky);
#pragma unroll
        for (int e = 0; e < 9; ++e) rots[w][j][e] = R[e];
        if (j >= 1) {
            int base = (j - 1) * 9;
#pragma unroll
            for (int e = 0; e < 9; ++e) {
                float val = R[e] - ((e == 0 || e == 4 || e == 8) ? 1.0f : 0.0f);
                writeA(ABsw, b, base + e, val);
            }
        }
#pragma unroll
        for (int c3 = 0; c3 < 3; ++c3) {
            float acc = Jc[(j * 3 + c3) * 11 + 10];
#pragma unroll
            for (int s10 = 0; s10 < 10; ++s10)
                acc += Jc[(j * 3 + c3) * 11 + s10] * betas[b * 10 + s10];
            thj[w][j][c3] = acc;
        }
    } else if (l < 41) {
        int k = 207 + (l - 24);
        float val;
        if (l < 34)       val = betas[b * 10 + (l - 24)];
        else if (l == 34) val = 1.0f;
        else              val = 0.0f;
        writeA(ABsw, b, k, val);
    }
    __syncthreads();

    if (l < 16) {
        int m = l >> 2, n = l & 3;
        float v;
        if (m < 3) v = (n < 3) ? rots[w][0][m * 3 + n] : thj[w][0][m];
        else       v = (n == 3) ? 1.0f : 0.0f;
        res[w][0][l] = v;
    }
    __syncthreads();
#pragma unroll
    for (int i = 1; i < NJ; ++i) {
        int p = c_par[i];
        if (l < 16) {
            int m = l >> 2, n = l & 3;
            float acc = 0.0f;
#pragma unroll
            for (int k3 = 0; k3 < 3; ++k3) {
                float relkn = (n < 3) ? rots[w][i][k3 * 3 + n]
                                      : (thj[w][i][k3] - thj[w][p][k3]);
                acc += res[w][p][m * 4 + k3] * relkn;
            }
            if (n == 3) acc += res[w][p][m * 4 + 3];
            res[w][i][l] = acc;
        }
        __syncthreads();
    }

    if (l < NJ) {
        int j = l;
#pragma unroll
        for (int c3 = 0; c3 < 3; ++c3)
            out[JTR_OFF + b * 72 + j * 3 + c3] = res[w][j][c3 * 4 + 3] + trans[b * 3 + c3];
    }
    // G2B: 12 components mc = m*4+n, K=32 (j=24..31 zero), bf16 A-operand swizzle
    for (int k = l; k < 384; k += 64) {
        int mc = k >> 5, j = k & 31;
        int m = mc >> 2, n = mc & 3;
        float v = 0.0f;
        if (j < NJ) {
            if (n < 3) v = res[w][j][m * 4 + n];
            else v = res[w][j][m * 4 + 3] - (res[w][j][m * 4 + 0] * thj[w][j][0] +
                                             res[w][j][m * 4 + 1] * thj[w][j][1] +
                                             res[w][j][m * 4 + 2] * thj[w][j][2]);
        }
        __hip_bfloat16 h = __float2bfloat16(v);
        G2B[mc * 32768 + ((((b >> 6) * 4) + (j >> 3)) * 64 + (b & 63)) * 8 + (j & 7)] = h;
    }
}

// ---------------------------------------------------------------------------
// k2g: fused pose-GEMM + MFMA blend.  A = batches (M), B = verts (N).
// Block: 64b x 64v x 3c, 4 waves (2x2), K-loop 7 x 32, mfma 16x16x32 bf16.
// K-loop: round-1 form (load->ds_write per kt, launch_bounds(256,3)) — the
// reg-prefetch + 4 blocks/CU variant tripled FETCH_SIZE (L2 thrash).
// Store path: TCC streams each store instruction as masked sector writes
// with NO cross-instruction merge (WRITE_SIZE = 3.08x ideal with 3 dword
// insts/span, 2.01x with dwordx2+dword). Fix: blend results (+trans) go to
// an LDS tile [64 rows][204 f32] (row = one batch, 64 verts * xyz = 768 B),
// one barrier, then each row is stored by 48 lanes x dwordx4 in a SINGLE
// instruction — every interior 32 B sector fully covered per instruction.
// (Round-3 bug: readback only covered 48 of 192 floats/row — fixed: fbase
// = lane*4, lanes 0..47, 16 rows per wave.)
// ---------------------------------------------------------------------------
__launch_bounds__(256, 3)
__global__ void k2g(const __hip_bfloat16* __restrict__ pdBsw,
                    const __hip_bfloat16* __restrict__ ABsw,
                    const __hip_bfloat16* __restrict__ G2B,
                    const __hip_bfloat16* __restrict__ wtsB,
                    const float* __restrict__ trans,
                    float* __restrict__ outp)
{
    // overlay: K-loop uses As (12 KB) + Bs (4 KB); epilogue reuses the whole
    // buffer as a 64x204 f32 output tile (52224 B). 3 blocks/CU: 153 KB LDS.
    __shared__ __align__(16) char smem[64 * 204 * 4];
    ushort* As = (ushort*)smem;               // verts,  3*4*64*8 ushorts
    ushort* Bs = (ushort*)(smem + 12288);     // batch,  4*64*8 ushorts
    float*  outs = (float*)smem;              // epilogue output tile [64][204]

    int tid = threadIdx.x;
    int vtile = blockIdx.x;      // 0..107
    int btile = blockIdx.y;      // 0..15
    int wid = tid >> 6, lane = tid & 63;
    int waveb = wid & 1, wavev = wid >> 1;
    int kq = lane >> 4, l15 = lane & 15;

    const float4* pA4 = (const float4*)pdBsw;
    const float4* pB4 = (const float4*)ABsw;

    f32x4 acc[3][2][2] = {};   // [c][mi=b-sub][ni=v-sub]

    int aoff = (kq * 64 + waveb * 32 + l15) * 8;      // batch frag (from Bs) + mi*128
    int boff = (kq * 64 + wavev * 32 + l15) * 8;      // vert frag (from As) + ni*128 + c*2048

    for (int kt = 0; kt < 7; ++kt) {
        int abase = (vtile * 7 + kt) * 768;
        int bbase = (btile * 7 + kt) * 256;
        ((float4*)As)[tid]       = pA4[abase + tid];
        ((float4*)As)[tid + 256] = pA4[abase + tid + 256];
        ((float4*)As)[tid + 512] = pA4[abase + tid + 512];
        ((float4*)Bs)[tid]       = pB4[bbase + tid];
        __syncthreads();

        bf16x8 af[2];
#pragma unroll
        for (int mi = 0; mi < 2; ++mi)
            af[mi] = *(const bf16x8*)&Bs[aoff + mi * 128];
#pragma unroll
        for (int c = 0; c < 3; ++c) {
            bf16x8 bfr[2];
#pragma unroll
            for (int ni = 0; ni < 2; ++ni)
                bfr[ni] = *(const bf16x8*)&As[boff + c * 2048 + ni * 128];
#pragma unroll
            for (int mi = 0; mi < 2; ++mi)
#pragma unroll
                for (int ni = 0; ni < 2; ++ni)
                    acc[c][mi][ni] = __builtin_amdgcn_mfma_f32_16x16x32_bf16(
                        af[mi], bfr[ni], acc[c][mi][ni], 0, 0, 0);
        }
        __syncthreads();
    }
    // all As/Bs reads drained by the final barrier — safe to overlay outs.

    // ---- blend epilogue ----
    // wts B-frags (col = v), one per ni — same for all 12 components
    bf16x8 wf[2];
#pragma unroll
    for (int ni = 0; ni < 2; ++ni)
        wf[ni] = *(const bf16x8*)&wtsB[(((vtile * 4 + kq) * 64) +
                                        wavev * 32 + ni * 16 + l15) * 8];

    int bframe = ((btile * 4 + kq) * 64 + waveb * 32 + l15) * 8;  // + mi*128

#pragma unroll
    for (int mi = 0; mi < 2; ++mi) {
#pragma unroll
        for (int m = 0; m < 3; ++m) {
            f32x4 T[4][2] = {};
#pragma unroll
            for (int c4 = 0; c4 < 4; ++c4) {
                int mc = m * 4 + c4;
                bf16x8 gf = *(const bf16x8*)&G2B[mc * 32768 + bframe + mi * 128];
#pragma unroll
                for (int ni = 0; ni < 2; ++ni)
                    T[c4][ni] = __builtin_amdgcn_mfma_f32_16x16x32_bf16(
                        gf, wf[ni], T[c4][ni], 0, 0, 0);
            }
            // write blended component (+trans) into the LDS output tile
#pragma unroll
            for (int ni = 0; ni < 2; ++ni) {
                int vl = wavev * 32 + ni * 16 + l15;
#pragma unroll
                for (int r = 0; r < 4; ++r) {
                    int bl = waveb * 32 + mi * 16 + (kq << 2) + r;
                    int b  = btile * 64 + bl;
                    float x = acc[0][mi][ni][r];
                    float y = acc[1][mi][ni][r];
                    float z = acc[2][mi][ni][r];
                    outs[bl * 204 + vl * 3 + m] =
                        T[3][ni][r] + T[0][ni][r] * x + T[1][ni][r] * y +
                        T[2][ni][r] * z + trans[b * 3 + m];
                }
            }
        }
    }
    __syncthreads();

    // ---- dense readback: one full 768 B row (64 verts * xyz) per store
    // instruction — 48 lanes x dwordx4; 16 rows per wave. ----
    int fvalid = (NV - vtile * 64) * 3;           // floats valid in this span
    if (fvalid > 192) fvalid = 192;
    if (lane < 48) {
        int fbase = lane * 4;
#pragma unroll
        for (int it = 0; it < 16; ++it) {
            int bl = wid * 16 + it;
            int b  = btile * 64 + bl;
            const float* src = &outs[bl * 204 + fbase];
            float* dst = &outp[(size_t)b * V3 + (size_t)vtile * 192 + fbase];
            if (fbase + 4 <= fvalid) {
                *(f4u*)dst = *(const f4u*)src;
            } else {
#pragma unroll
                for (int k2 = 0; k2 < 4; ++k2)
                    if (fbase + k2 < fvalid) dst[k2] = src[k2];
            }
        }
    }
}

extern "C" void kernel_launch(void* const* d_in, const int* in_sizes, int n_in,
                              void* d_out, int out_size, void* d_ws, size_t ws_size,
                              hipStream_t stream)
{
    const float* pose   = (const float*)d_in[0];
    const float* betas  = (const float*)d_in[1];
    const float* trans  = (const float*)d_in[2];
    const float* vtempl = (const float*)d_in[3];
    const float* shdirs = (const float*)d_in[4];
    const float* pdirs  = (const float*)d_in[5];
    const float* Jreg   = (const float*)d_in[6];
    const float* wts    = (const float*)d_in[7];
    float* out = (float*)d_out;
    char* ws = (char*)d_ws;

    float* Jc              = (float*)(ws);                      // 792 fl (4 KB)
    __hip_bfloat16* ABsw   = (__hip_bfloat16*)(ws + 4096);      // 229376 bf16
    __hip_bfloat16* G2B    = (__hip_bfloat16*)(ws + 462848);    // 393216 bf16
    __hip_bfloat16* wtsB   = (__hip_bfloat16*)(ws + 1249280);   // 221184 bf16
    __hip_bfloat16* pdBsw  = (__hip_bfloat16*)(ws + 1691648);   // 4644864 bf16

    hipMemsetAsync(Jc, 0, NJ * 33 * sizeof(float), stream);
    hipLaunchKernelGGL(k0, dim3(NJ, 4), dim3(256), 0, stream, Jreg, vtempl, shdirs, Jc);
    hipLaunchKernelGGL(kpack, dim3(2268), dim3(256), 0, stream, pdirs, shdirs, vtempl, pdBsw);
    hipLaunchKernelGGL(kwB, dim3(108), dim3(256), 0, stream, wts, wtsB);
    hipLaunchKernelGGL(k1, dim3(NB / 4), dim3(256), 0, stream,
                       pose, betas, trans, Jc, ABsw, G2B, out);
    hipLaunchKernelGGL(k2g, dim3(108, 16), dim3(256), 0, stream,
                       pdBsw, ABsw, G2B, wtsB, trans, out);
}

// Round 5
// 191.094 us; speedup vs baseline: 1.1136x; 1.0083x over previous
//
#include <hip/hip_runtime.h>
#include <hip/hip_bf16.h>

#define NJ 24
#define NV 6890
#define NB 1024
#define V3 (NV*3)         // 20670 floats per batch in out
#define JTR_OFF (NB*NV*3)

typedef __attribute__((ext_vector_type(8))) short bf16x8;
typedef __attribute__((ext_vector_type(4))) float f32x4;
typedef float f4u __attribute__((ext_vector_type(4), aligned(4)));

__constant__ int c_par[NJ] = {-1,0,0,0,1,2,3,4,5,6,7,8,9,9,9,12,13,14,16,17,18,19,20,21};

// ---------------------------------------------------------------------------
// k0: fold joint regressor: Jc[j][c][s], s<10: Jreg@shapedirs, s=10: Jreg@tmpl
// ---------------------------------------------------------------------------
__global__ void k0(const float* __restrict__ Jreg, const float* __restrict__ vtempl,
                   const float* __restrict__ shdirs, float* __restrict__ Jc)
{
    int j = blockIdx.x;
    float acc[33];
#pragma unroll
    for (int i = 0; i < 33; ++i) acc[i] = 0.0f;

    for (int v = blockIdx.y * 256 + threadIdx.x; v < NV; v += 1024) {
        float r = Jreg[j * NV + v];
#pragma unroll
        for (int c = 0; c < 3; ++c) {
            acc[c * 11 + 10] += r * vtempl[v * 3 + c];
            const float* sd = &shdirs[(v * 3 + c) * 10];
#pragma unroll
            for (int s = 0; s < 10; ++s) acc[c * 11 + s] += r * sd[s];
        }
    }
#pragma unroll
    for (int i = 0; i < 33; ++i) {
        float x = acc[i];
        for (int o = 32; o > 0; o >>= 1) x += __shfl_down(x, o, 64);
        acc[i] = x;
    }
    __shared__ float red[4][33];
    int w = threadIdx.x >> 6, l = threadIdx.x & 63;
    if (l == 0) {
#pragma unroll
        for (int i = 0; i < 33; ++i) red[w][i] = acc[i];
    }
    __syncthreads();
    if (threadIdx.x < 33) {
        float s = red[0][threadIdx.x] + red[1][threadIdx.x] +
                  red[2][threadIdx.x] + red[3][threadIdx.x];
        atomicAdd(&Jc[j * 33 + threadIdx.x], s);
    }
}

// ---------------------------------------------------------------------------
// kpack: build pdB_sw (bf16), pre-swizzled to the k2g LDS image order:
//   chunk cid = (((vtile*7 + kt)*3 + c)*4 + kq)*64 + v64 ; each chunk = 8 k.
// ---------------------------------------------------------------------------
__global__ void kpack(const float* __restrict__ pdirs, const float* __restrict__ shdirs,
                      const float* __restrict__ vtempl, __hip_bfloat16* __restrict__ pdBsw)
{
    int cid = blockIdx.x * 256 + threadIdx.x;   // < 580608
    int v64 = cid & 63;
    int t = cid >> 6;
    int kq = t & 3; t >>= 2;
    int c = t % 3; t /= 3;
    int kt = t % 7;
    int vt = t / 7;
    int v = vt * 64 + v64;

    ushort tmp[8] __attribute__((aligned(16)));
#pragma unroll
    for (int j = 0; j < 8; ++j) {
        int k = kt * 32 + kq * 8 + j;
        float val = 0.0f;
        if (v < NV) {
            if (k < 207)       val = pdirs[(v * 3 + c) * 207 + k];
            else if (k < 217)  val = shdirs[(v * 3 + c) * 10 + (k - 207)];
            else if (k == 217) val = vtempl[v * 3 + c];
        }
        __hip_bfloat16 h = __float2bfloat16(val);
        tmp[j] = *(ushort*)&h;
    }
    ((float4*)pdBsw)[cid] = *(const float4*)tmp;
}

// ---------------------------------------------------------------------------
// kwB: weights -> bf16 B-operand swizzle. chunk = (vtile*4 + kq)*64 + v64,
// 8 j each, K=32 (24 j + 8 zero pad).  27648 chunks.
// ---------------------------------------------------------------------------
__global__ void kwB(const float* __restrict__ wts, __hip_bfloat16* __restrict__ wtsB)
{
    int t = blockIdx.x * 256 + threadIdx.x;     // < 27648
    int v64 = t & 63;
    int kq = (t >> 6) & 3;
    int vt = t >> 8;
    int v = vt * 64 + v64;

    ushort tmp[8] __attribute__((aligned(16)));
#pragma unroll
    for (int j8 = 0; j8 < 8; ++j8) {
        int j = kq * 8 + j8;
        float val = (v < NV && j < NJ) ? wts[v * NJ + j] : 0.0f;
        __hip_bfloat16 h = __float2bfloat16(val);
        tmp[j8] = *(ushort*)&h;
    }
    ((float4*)wtsB)[t] = *(const float4*)tmp;
}

// ---------------------------------------------------------------------------
// k1: Rodrigues, A (bf16, swizzled), th_j, kinematic chain, G2B (bf16,
// A-operand swizzled, 12 components), th_jtr. One wave/batch, 4 batches/block.
// ABsw chunk: ((btile*7 + kt)*4 + kq)*64 + b64, 8 k each.
// G2B[mc] chunk: ((btile*4 + jq)*64 + b64)*8 + j7, mc stride 32768 elements.
// ---------------------------------------------------------------------------
__device__ __forceinline__ void writeA(__hip_bfloat16* ABsw, int b, int k, float val)
{
    int btile = b >> 6, b6 = b & 63, kt = k >> 5, kq = (k >> 3) & 3, j = k & 7;
    __hip_bfloat16 h = __float2bfloat16(val);
    ABsw[((((btile * 7) + kt) * 4 + kq) * 64 + b6) * 8 + j] = h;
}

__global__ void k1(const float* __restrict__ pose, const float* __restrict__ betas,
                   const float* __restrict__ trans, const float* __restrict__ Jc,
                   __hip_bfloat16* __restrict__ ABsw, __hip_bfloat16* __restrict__ G2B,
                   float* __restrict__ out)
{
    __shared__ float rots[4][NJ][9];
    __shared__ float thj [4][NJ][3];
    __shared__ float res [4][NJ][16];

    int w = threadIdx.x >> 6;
    int l = threadIdx.x & 63;
    int b = blockIdx.x * 4 + w;

    if (l < NJ) {
        int j = l;
        float ax = pose[b * 72 + j * 3 + 0];
        float ay = pose[b * 72 + j * 3 + 1];
        float az = pose[b * 72 + j * 3 + 2];
        float theta = sqrtf(ax * ax + ay * ay + az * az + 1e-8f);
        float inv = 1.0f / theta;
        float kx = ax * inv, ky = ay * inv, kz = az * inv;
        float c = cosf(theta), s = sinf(theta), mc = 1.0f - c;
        float R[9];
        R[0] = 1.0f - mc * (ky * ky + kz * kz);
        R[1] = -s * kz + mc * (kx * ky);
        R[2] =  s * ky + mc * (kx * kz);
        R[3] =  s * kz + mc * (kx * ky);
        R[4] = 1.0f - mc * (kx * kx + kz * kz);
        R[5] = -s * kx + mc * (ky * kz);
        R[6] = -s * ky + mc * (kx * kz);
        R[7] =  s * kx + mc * (ky * kz);
        R[8] = 1.0f - mc * (kx * kx + ky * ky);
#pragma unroll
        for (int e = 0; e < 9; ++e) rots[w][j][e] = R[e];
        if (j >= 1) {
            int base = (j - 1) * 9;
#pragma unroll
            for (int e = 0; e < 9; ++e) {
                float val = R[e] - ((e == 0 || e == 4 || e == 8) ? 1.0f : 0.0f);
                writeA(ABsw, b, base + e, val);
            }
        }
#pragma unroll
        for (int c3 = 0; c3 < 3; ++c3) {
            float acc = Jc[(j * 3 + c3) * 11 + 10];
#pragma unroll
            for (int s10 = 0; s10 < 10; ++s10)
                acc += Jc[(j * 3 + c3) * 11 + s10] * betas[b * 10 + s10];
            thj[w][j][c3] = acc;
        }
    } else if (l < 41) {
        int k = 207 + (l - 24);
        float val;
        if (l < 34)       val = betas[b * 10 + (l - 24)];
        else if (l == 34) val = 1.0f;
        else              val = 0.0f;
        writeA(ABsw, b, k, val);
    }
    __syncthreads();

    if (l < 16) {
        int m = l >> 2, n = l & 3;
        float v;
        if (m < 3) v = (n < 3) ? rots[w][0][m * 3 + n] : thj[w][0][m];
        else       v = (n == 3) ? 1.0f : 0.0f;
        res[w][0][l] = v;
    }
    __syncthreads();
#pragma unroll
    for (int i = 1; i < NJ; ++i) {
        int p = c_par[i];
        if (l < 16) {
            int m = l >> 2, n = l & 3;
            float acc = 0.0f;
#pragma unroll
            for (int k3 = 0; k3 < 3; ++k3) {
                float relkn = (n < 3) ? rots[w][i][k3 * 3 + n]
                                      : (thj[w][i][k3] - thj[w][p][k3]);
                acc += res[w][p][m * 4 + k3] * relkn;
            }
            if (n == 3) acc += res[w][p][m * 4 + 3];
            res[w][i][l] = acc;
        }
        __syncthreads();
    }

    if (l < NJ) {
        int j = l;
#pragma unroll
        for (int c3 = 0; c3 < 3; ++c3)
            out[JTR_OFF + b * 72 + j * 3 + c3] = res[w][j][c3 * 4 + 3] + trans[b * 3 + c3];
    }
    // G2B: 12 components mc = m*4+n, K=32 (j=24..31 zero), bf16 A-operand swizzle
    for (int k = l; k < 384; k += 64) {
        int mc = k >> 5, j = k & 31;
        int m = mc >> 2, n = mc & 3;
        float v = 0.0f;
        if (j < NJ) {
            if (n < 3) v = res[w][j][m * 4 + n];
            else v = res[w][j][m * 4 + 3] - (res[w][j][m * 4 + 0] * thj[w][j][0] +
                                             res[w][j][m * 4 + 1] * thj[w][j][1] +
                                             res[w][j][m * 4 + 2] * thj[w][j][2]);
        }
        __hip_bfloat16 h = __float2bfloat16(v);
        G2B[mc * 32768 + ((((b >> 6) * 4) + (j >> 3)) * 64 + (b & 63)) * 8 + (j & 7)] = h;
    }
}

// ---------------------------------------------------------------------------
// k2g: fused pose-GEMM + MFMA blend.  A = batches (M), B = verts (N).
// Block: 64b x 64v x 3c, 4 waves (2x2), K-loop 7 x 32, mfma 16x16x32 bf16.
// K-loop: round-1 form (load->ds_write per kt) — reg-prefetch @4 blocks/CU
// tripled FETCH_SIZE (L2 thrash).
// Store path (sector-dense): TCC streams each store instruction as masked
// sector writes with NO cross-instruction merge (WRITE = 3.08x ideal with
// 3 dword insts/span, 2.01x with dwordx2+dword). Blend results (+trans) go
// through an LDS transpose tile; each 768 B batch-row is stored by 48
// lanes x dwordx4 in a SINGLE instruction.
// v5: LDS tile halved to 32 rows x 204 f32 = 26112 B, epilogue in 2 passes.
// Round-4's 64-row tile (52 KB) silently dropped residency 3->2 blocks/CU
// (occupancy 35%->19.8%) and gave back the write-fix gain — k2g is
// latency-bound (hbm 769 GB/s, MfmaUtil 10%), so occupancy is the lever.
// All 48 blend MFMAs run upfront into res3[2][2][4][3] (+48 VGPR, under
// the 170 cap at 3 waves/SIMD); passes only move regs->LDS->HBM.
// ---------------------------------------------------------------------------
__launch_bounds__(256, 3)
__global__ void k2g(const __hip_bfloat16* __restrict__ pdBsw,
                    const __hip_bfloat16* __restrict__ ABsw,
                    const __hip_bfloat16* __restrict__ G2B,
                    const __hip_bfloat16* __restrict__ wtsB,
                    const float* __restrict__ trans,
                    float* __restrict__ outp)
{
    // overlay: K-loop uses As (12 KB) + Bs (4 KB); epilogue reuses the buffer
    // as a 32x204 f32 half-tile (26112 B). 3 blocks/CU: 76.5 KB LDS total.
    __shared__ __align__(16) char smem[32 * 204 * 4];
    ushort* As = (ushort*)smem;               // verts,  3*4*64*8 ushorts (12 KB)
    ushort* Bs = (ushort*)(smem + 12288);     // batch,  4*64*8 ushorts (4 KB)
    float*  outs = (float*)smem;              // epilogue half-tile [32][204]

    int tid = threadIdx.x;
    int vtile = blockIdx.x;      // 0..107
    int btile = blockIdx.y;      // 0..15
    int wid = tid >> 6, lane = tid & 63;
    int waveb = wid & 1, wavev = wid >> 1;
    int kq = lane >> 4, l15 = lane & 15;

    const float4* pA4 = (const float4*)pdBsw;
    const float4* pB4 = (const float4*)ABsw;

    f32x4 acc[3][2][2] = {};   // [c][mi=b-sub][ni=v-sub]

    int aoff = (kq * 64 + waveb * 32 + l15) * 8;      // batch frag (from Bs) + mi*128
    int boff = (kq * 64 + wavev * 32 + l15) * 8;      // vert frag (from As) + ni*128 + c*2048

    for (int kt = 0; kt < 7; ++kt) {
        int abase = (vtile * 7 + kt) * 768;
        int bbase = (btile * 7 + kt) * 256;
        ((float4*)As)[tid]       = pA4[abase + tid];
        ((float4*)As)[tid + 256] = pA4[abase + tid + 256];
        ((float4*)As)[tid + 512] = pA4[abase + tid + 512];
        ((float4*)Bs)[tid]       = pB4[bbase + tid];
        __syncthreads();

        bf16x8 af[2];
#pragma unroll
        for (int mi = 0; mi < 2; ++mi)
            af[mi] = *(const bf16x8*)&Bs[aoff + mi * 128];
#pragma unroll
        for (int c = 0; c < 3; ++c) {
            bf16x8 bfr[2];
#pragma unroll
            for (int ni = 0; ni < 2; ++ni)
                bfr[ni] = *(const bf16x8*)&As[boff + c * 2048 + ni * 128];
#pragma unroll
            for (int mi = 0; mi < 2; ++mi)
#pragma unroll
                for (int ni = 0; ni < 2; ++ni)
                    acc[c][mi][ni] = __builtin_amdgcn_mfma_f32_16x16x32_bf16(
                        af[mi], bfr[ni], acc[c][mi][ni], 0, 0, 0);
        }
        __syncthreads();
    }
    // all As/Bs reads drained by the final barrier — safe to overlay outs.

    // ---- blend: all 48 mini-MFMAs upfront, results held in registers ----
    bf16x8 wf[2];
#pragma unroll
    for (int ni = 0; ni < 2; ++ni)
        wf[ni] = *(const bf16x8*)&wtsB[(((vtile * 4 + kq) * 64) +
                                        wavev * 32 + ni * 16 + l15) * 8];

    int bframe = ((btile * 4 + kq) * 64 + waveb * 32 + l15) * 8;  // + mi*128

    float res3[2][2][4][3];    // [mi][ni][r][m]
#pragma unroll
    for (int mi = 0; mi < 2; ++mi) {
#pragma unroll
        for (int m = 0; m < 3; ++m) {
            f32x4 T[4][2] = {};
#pragma unroll
            for (int c4 = 0; c4 < 4; ++c4) {
                int mc = m * 4 + c4;
                bf16x8 gf = *(const bf16x8*)&G2B[mc * 32768 + bframe + mi * 128];
#pragma unroll
                for (int ni = 0; ni < 2; ++ni)
                    T[c4][ni] = __builtin_amdgcn_mfma_f32_16x16x32_bf16(
                        gf, wf[ni], T[c4][ni], 0, 0, 0);
            }
#pragma unroll
            for (int ni = 0; ni < 2; ++ni) {
#pragma unroll
                for (int r = 0; r < 4; ++r) {
                    int bl = waveb * 32 + mi * 16 + (kq << 2) + r;
                    int b  = btile * 64 + bl;
                    float x = acc[0][mi][ni][r];
                    float y = acc[1][mi][ni][r];
                    float z = acc[2][mi][ni][r];
                    res3[mi][ni][r][m] = T[3][ni][r] + T[0][ni][r] * x +
                                         T[1][ni][r] * y + T[2][ni][r] * z +
                                         trans[b * 3 + m];
                }
            }
        }
    }

    // ---- 2-pass LDS transpose + sector-dense store ----
    int fvalid = (NV - vtile * 64) * 3;           // floats valid in this span
    if (fvalid > 192) fvalid = 192;
#pragma unroll
    for (int pass = 0; pass < 2; ++pass) {
        if (waveb == pass) {
            // this half's waves own rows pass*32 .. pass*32+31
#pragma unroll
            for (int mi = 0; mi < 2; ++mi) {
#pragma unroll
                for (int ni = 0; ni < 2; ++ni) {
                    int vl = wavev * 32 + ni * 16 + l15;
#pragma unroll
                    for (int r = 0; r < 4; ++r) {
                        int row = mi * 16 + (kq << 2) + r;   // 0..31
#pragma unroll
                        for (int m = 0; m < 3; ++m)
                            outs[row * 204 + vl * 3 + m] = res3[mi][ni][r][m];
                    }
                }
            }
        }
        __syncthreads();
        // readback: one full 768 B row per store instruction (48 lanes x
        // dwordx4); 8 rows per wave.
        if (lane < 48) {
            int fbase = lane * 4;
#pragma unroll
            for (int it = 0; it < 8; ++it) {
                int bl = wid * 8 + it;                       // 0..31
                int b  = btile * 64 + pass * 32 + bl;
                const float* src = &outs[bl * 204 + fbase];
                float* dst = &outp[(size_t)b * V3 + (size_t)vtile * 192 + fbase];
                if (fbase + 4 <= fvalid) {
                    *(f4u*)dst = *(const f4u*)src;
                } else {
#pragma unroll
                    for (int k2 = 0; k2 < 4; ++k2)
                        if (fbase + k2 < fvalid) dst[k2] = src[k2];
                }
            }
        }
        if (pass == 0) __syncthreads();   // protect rows before pass-1 overwrite
    }
}

extern "C" void kernel_launch(void* const* d_in, const int* in_sizes, int n_in,
                              void* d_out, int out_size, void* d_ws, size_t ws_size,
                              hipStream_t stream)
{
    const float* pose   = (const float*)d_in[0];
    const float* betas  = (const float*)d_in[1];
    const float* trans  = (const float*)d_in[2];
    const float* vtempl = (const float*)d_in[3];
    const float* shdirs = (const float*)d_in[4];
    const float* pdirs  = (const float*)d_in[5];
    const float* Jreg   = (const float*)d_in[6];
    const float* wts    = (const float*)d_in[7];
    float* out = (float*)d_out;
    char* ws = (char*)d_ws;

    float* Jc              = (float*)(ws);                      // 792 fl (4 KB)
    __hip_bfloat16* ABsw   = (__hip_bfloat16*)(ws + 4096);      // 229376 bf16
    __hip_bfloat16* G2B    = (__hip_bfloat16*)(ws + 462848);    // 393216 bf16
    __hip_bfloat16* wtsB   = (__hip_bfloat16*)(ws + 1249280);   // 221184 bf16
    __hip_bfloat16* pdBsw  = (__hip_bfloat16*)(ws + 1691648);   // 4644864 bf16

    hipMemsetAsync(Jc, 0, NJ * 33 * sizeof(float), stream);
    hipLaunchKernelGGL(k0, dim3(NJ, 4), dim3(256), 0, stream, Jreg, vtempl, shdirs, Jc);
    hipLaunchKernelGGL(kpack, dim3(2268), dim3(256), 0, stream, pdirs, shdirs, vtempl, pdBsw);
    hipLaunchKernelGGL(kwB, dim3(108), dim3(256), 0, stream, wts, wtsB);
    hipLaunchKernelGGL(k1, dim3(NB / 4), dim3(256), 0, stream,
                       pose, betas, trans, Jc, ABsw, G2B, out);
    hipLaunchKernelGGL(k2g, dim3(108, 16), dim3(256), 0, stream,
                       pdBsw, ABsw, G2B, wtsB, trans, out);
}

// Round 7
// 186.120 us; speedup vs baseline: 1.1433x; 1.0267x over previous
//
#include <hip/hip_runtime.h>
#include <hip/hip_bf16.h>

#define NJ 24
#define NV 6890
#define NB 1024
#define V3 (NV*3)         // 20670 floats per batch in out
#define JTR_OFF (NB*NV*3)

typedef __attribute__((ext_vector_type(8))) short bf16x8;
typedef __attribute__((ext_vector_type(4))) float f32x4;
typedef float f4u __attribute__((ext_vector_type(4), aligned(4)));

__constant__ int c_par[NJ] = {-1,0,0,0,1,2,3,4,5,6,7,8,9,9,9,12,13,14,16,17,18,19,20,21};

// ---------------------------------------------------------------------------
// k0: fold joint regressor: Jc[j][c][s], s<10: Jreg@shapedirs, s=10: Jreg@tmpl
// ---------------------------------------------------------------------------
__global__ void k0(const float* __restrict__ Jreg, const float* __restrict__ vtempl,
                   const float* __restrict__ shdirs, float* __restrict__ Jc)
{
    int j = blockIdx.x;
    float acc[33];
#pragma unroll
    for (int i = 0; i < 33; ++i) acc[i] = 0.0f;

    for (int v = blockIdx.y * 256 + threadIdx.x; v < NV; v += 1024) {
        float r = Jreg[j * NV + v];
#pragma unroll
        for (int c = 0; c < 3; ++c) {
            acc[c * 11 + 10] += r * vtempl[v * 3 + c];
            const float* sd = &shdirs[(v * 3 + c) * 10];
#pragma unroll
            for (int s = 0; s < 10; ++s) acc[c * 11 + s] += r * sd[s];
        }
    }
#pragma unroll
    for (int i = 0; i < 33; ++i) {
        float x = acc[i];
        for (int o = 32; o > 0; o >>= 1) x += __shfl_down(x, o, 64);
        acc[i] = x;
    }
    __shared__ float red[4][33];
    int w = threadIdx.x >> 6, l = threadIdx.x & 63;
    if (l == 0) {
#pragma unroll
        for (int i = 0; i < 33; ++i) red[w][i] = acc[i];
    }
    __syncthreads();
    if (threadIdx.x < 33) {
        float s = red[0][threadIdx.x] + red[1][threadIdx.x] +
                  red[2][threadIdx.x] + red[3][threadIdx.x];
        atomicAdd(&Jc[j * 33 + threadIdx.x], s);
    }
}

// ---------------------------------------------------------------------------
// kpack: build pdB_sw (bf16), pre-swizzled to the k2g LDS image order:
//   chunk cid = (((vtile*7 + kt)*3 + c)*4 + kq)*64 + v64 ; each chunk = 8 k.
// ---------------------------------------------------------------------------
__global__ void kpack(const float* __restrict__ pdirs, const float* __restrict__ shdirs,
                      const float* __restrict__ vtempl, __hip_bfloat16* __restrict__ pdBsw)
{
    int cid = blockIdx.x * 256 + threadIdx.x;   // < 580608
    int v64 = cid & 63;
    int t = cid >> 6;
    int kq = t & 3; t >>= 2;
    int c = t % 3; t /= 3;
    int kt = t % 7;
    int vt = t / 7;
    int v = vt * 64 + v64;

    ushort tmp[8] __attribute__((aligned(16)));
#pragma unroll
    for (int j = 0; j < 8; ++j) {
        int k = kt * 32 + kq * 8 + j;
        float val = 0.0f;
        if (v < NV) {
            if (k < 207)       val = pdirs[(v * 3 + c) * 207 + k];
            else if (k < 217)  val = shdirs[(v * 3 + c) * 10 + (k - 207)];
            else if (k == 217) val = vtempl[v * 3 + c];
        }
        __hip_bfloat16 h = __float2bfloat16(val);
        tmp[j] = *(ushort*)&h;
    }
    ((float4*)pdBsw)[cid] = *(const float4*)tmp;
}

// ---------------------------------------------------------------------------
// kwB: weights -> bf16 B-operand swizzle. chunk = (vtile*4 + kq)*64 + v64,
// 8 j each, K=32 (24 j + 8 zero pad).  27648 chunks.
// ---------------------------------------------------------------------------
__global__ void kwB(const float* __restrict__ wts, __hip_bfloat16* __restrict__ wtsB)
{
    int t = blockIdx.x * 256 + threadIdx.x;     // < 27648
    int v64 = t & 63;
    int kq = (t >> 6) & 3;
    int vt = t >> 8;
    int v = vt * 64 + v64;

    ushort tmp[8] __attribute__((aligned(16)));
#pragma unroll
    for (int j8 = 0; j8 < 8; ++j8) {
        int j = kq * 8 + j8;
        float val = (v < NV && j < NJ) ? wts[v * NJ + j] : 0.0f;
        __hip_bfloat16 h = __float2bfloat16(val);
        tmp[j8] = *(ushort*)&h;
    }
    ((float4*)wtsB)[t] = *(const float4*)tmp;
}

// ---------------------------------------------------------------------------
// k1: Rodrigues, A (bf16, swizzled), th_j, kinematic chain, G2B (bf16,
// A-operand swizzled, 12 components), th_jtr. One wave/batch, 4 batches/block.
// ABsw chunk: ((btile*7 + kt)*4 + kq)*64 + b64, 8 k each.
// G2B[mc] chunk: ((btile*4 + jq)*64 + b64)*8 + j7, mc stride 32768 elements.
// ---------------------------------------------------------------------------
__device__ __forceinline__ void writeA(__hip_bfloat16* ABsw, int b, int k, float val)
{
    int btile = b >> 6, b6 = b & 63, kt = k >> 5, kq = (k >> 3) & 3, j = k & 7;
    __hip_bfloat16 h = __float2bfloat16(val);
    ABsw[((((btile * 7) + kt) * 4 + kq) * 64 + b6) * 8 + j] = h;
}

__global__ void k1(const float* __restrict__ pose, const float* __restrict__ betas,
                   const float* __restrict__ trans, const float* __restrict__ Jc,
                   __hip_bfloat16* __restrict__ ABsw, __hip_bfloat16* __restrict__ G2B,
                   float* __restrict__ out)
{
    __shared__ float rots[4][NJ][9];
    __shared__ float thj [4][NJ][3];
    __shared__ float res [4][NJ][16];

    int w = threadIdx.x >> 6;
    int l = threadIdx.x & 63;
    int b = blockIdx.x * 4 + w;

    if (l < NJ) {
        int j = l;
        float ax = pose[b * 72 + j * 3 + 0];
        float ay = pose[b * 72 + j * 3 + 1];
        float az = pose[b * 72 + j * 3 + 2];
        float theta = sqrtf(ax * ax + ay * ay + az * az + 1e-8f);
        float inv = 1.0f / theta;
        float kx = ax * inv, ky = ay * inv, kz = az * inv;
        float c = cosf(theta), s = sinf(theta), mc = 1.0f - c;
        float R[9];
        R[0] = 1.0f - mc * (ky * ky + kz * kz);
        R[1] = -s * kz + mc * (kx * ky);
        R[2] =  s * ky + mc * (kx * kz);
        R[3] =  s * kz + mc * (kx * ky);
        R[4] = 1.0f - mc * (kx * kx + kz * kz);
        R[5] = -s * kx + mc * (ky * kz);
        R[6] = -s * ky + mc * (kx * kz);
        R[7] =  s * kx + mc * (ky * kz);
        R[8] = 1.0f - mc * (kx * kx + ky * ky);
#pragma unroll
        for (int e = 0; e < 9; ++e) rots[w][j][e] = R[e];
        if (j >= 1) {
            int base = (j - 1) * 9;
#pragma unroll
            for (int e = 0; e < 9; ++e) {
                float val = R[e] - ((e == 0 || e == 4 || e == 8) ? 1.0f : 0.0f);
                writeA(ABsw, b, base + e, val);
            }
        }
#pragma unroll
        for (int c3 = 0; c3 < 3; ++c3) {
            float acc = Jc[(j * 3 + c3) * 11 + 10];
#pragma unroll
            for (int s10 = 0; s10 < 10; ++s10)
                acc += Jc[(j * 3 + c3) * 11 + s10] * betas[b * 10 + s10];
            thj[w][j][c3] = acc;
        }
    } else if (l < 41) {
        int k = 207 + (l - 24);
        float val;
        if (l < 34)       val = betas[b * 10 + (l - 24)];
        else if (l == 34) val = 1.0f;
        else              val = 0.0f;
        writeA(ABsw, b, k, val);
    }
    __syncthreads();

    if (l < 16) {
        int m = l >> 2, n = l & 3;
        float v;
        if (m < 3) v = (n < 3) ? rots[w][0][m * 3 + n] : thj[w][0][m];
        else       v = (n == 3) ? 1.0f : 0.0f;
        res[w][0][l] = v;
    }
    __syncthreads();
#pragma unroll
    for (int i = 1; i < NJ; ++i) {
        int p = c_par[i];
        if (l < 16) {
            int m = l >> 2, n = l & 3;
            float acc = 0.0f;
#pragma unroll
            for (int k3 = 0; k3 < 3; ++k3) {
                float relkn = (n < 3) ? rots[w][i][k3 * 3 + n]
                                      : (thj[w][i][k3] - thj[w][p][k3]);
                acc += res[w][p][m * 4 + k3] * relkn;
            }
            if (n == 3) acc += res[w][p][m * 4 + 3];
            res[w][i][l] = acc;
        }
        __syncthreads();
    }

    if (l < NJ) {
        int j = l;
#pragma unroll
        for (int c3 = 0; c3 < 3; ++c3)
            out[JTR_OFF + b * 72 + j * 3 + c3] = res[w][j][c3 * 4 + 3] + trans[b * 3 + c3];
    }
    // G2B: 12 components mc = m*4+n, K=32 (j=24..31 zero), bf16 A-operand swizzle
    for (int k = l; k < 384; k += 64) {
        int mc = k >> 5, j = k & 31;
        int m = mc >> 2, n = mc & 3;
        float v = 0.0f;
        if (j < NJ) {
            if (n < 3) v = res[w][j][m * 4 + n];
            else v = res[w][j][m * 4 + 3] - (res[w][j][m * 4 + 0] * thj[w][j][0] +
                                             res[w][j][m * 4 + 1] * thj[w][j][1] +
                                             res[w][j][m * 4 + 2] * thj[w][j][2]);
        }
        __hip_bfloat16 h = __float2bfloat16(v);
        G2B[mc * 32768 + ((((b >> 6) * 4) + (j >> 3)) * 64 + (b & 63)) * 8 + (j & 7)] = h;
    }
}

// ---------------------------------------------------------------------------
// k2g: fused pose-GEMM + MFMA blend.  A = batches (M), B = verts (N).
// Block: 64b x 64v x 3c, 4 waves (2x2), K-loop 7 x 32, mfma 16x16x32 bf16.
// v6 (resubmit — round-6 bench was an infra failure, never measured):
// XCD-aware block remap (T1). Diagnosis: rounds 1/4/5 all ~52 us with
// WRITE 171->~95 MB and occupancy 20->34% — invariant bottleneck is the
// K-loop read path. With (108,16) x-fastest dispatch, the 16 btile-reuses
// of a vtile's 86 KB pdBsw slice are 108 blocks apart: the full 9.3 MB
// cycles through each XCD's 4 MB L2 between reuses -> every A-load is an
// L2 miss served from L3 (~600+ cyc) on the barrier-locked critical path.
// Remap: lin = (wgid&7)*216 + (wgid>>3); vtile = lin>>4; btile = lin&15 —
// all 16 btile-replicas of a vtile run back-to-back on ONE XCD; resident
// working set ~6 vtiles x 86 KB = 0.5 MB -> L2-hit reads.
// Store path (sector-dense, kept): TCC does masked sector writes with no
// cross-instruction merge (WRITE = 3.08x ideal @3 dword insts/span, 2.01x
// @dwordx2+dword). Blend (+trans) -> 32x204 f32 LDS half-tile, 2 passes;
// each 768 B batch-row stored by 48 lanes x dwordx4 in one instruction.
// ---------------------------------------------------------------------------
__launch_bounds__(256, 3)
__global__ void k2g(const __hip_bfloat16* __restrict__ pdBsw,
                    const __hip_bfloat16* __restrict__ ABsw,
                    const __hip_bfloat16* __restrict__ G2B,
                    const __hip_bfloat16* __restrict__ wtsB,
                    const float* __restrict__ trans,
                    float* __restrict__ outp)
{
    // overlay: K-loop uses As (12 KB) + Bs (4 KB); epilogue reuses the buffer
    // as a 32x204 f32 half-tile (26112 B). 3 blocks/CU: 76.5 KB LDS total.
    __shared__ __align__(16) char smem[32 * 204 * 4];
    ushort* As = (ushort*)smem;               // verts,  3*4*64*8 ushorts (12 KB)
    ushort* Bs = (ushort*)(smem + 12288);     // batch,  4*64*8 ushorts (4 KB)
    float*  outs = (float*)smem;              // epilogue half-tile [32][204]

    int tid = threadIdx.x;
    // XCD-aware remap: 1728 blocks = 8 XCDs x 216; round-robin -> contiguous
    // chunk per XCD, vtile-major inside the chunk (16 btiles consecutive).
    int wgid = blockIdx.y * 108 + blockIdx.x;
    int lin  = (wgid & 7) * 216 + (wgid >> 3);
    int vtile = lin >> 4;        // 0..107
    int btile = lin & 15;        // 0..15
    int wid = tid >> 6, lane = tid & 63;
    int waveb = wid & 1, wavev = wid >> 1;
    int kq = lane >> 4, l15 = lane & 15;

    const float4* pA4 = (const float4*)pdBsw;
    const float4* pB4 = (const float4*)ABsw;

    f32x4 acc[3][2][2] = {};   // [c][mi=b-sub][ni=v-sub]

    int aoff = (kq * 64 + waveb * 32 + l15) * 8;      // batch frag (from Bs) + mi*128
    int boff = (kq * 64 + wavev * 32 + l15) * 8;      // vert frag (from As) + ni*128 + c*2048

    for (int kt = 0; kt < 7; ++kt) {
        int abase = (vtile * 7 + kt) * 768;
        int bbase = (btile * 7 + kt) * 256;
        ((float4*)As)[tid]       = pA4[abase + tid];
        ((float4*)As)[tid + 256] = pA4[abase + tid + 256];
        ((float4*)As)[tid + 512] = pA4[abase + tid + 512];
        ((float4*)Bs)[tid]       = pB4[bbase + tid];
        __syncthreads();

        bf16x8 af[2];
#pragma unroll
        for (int mi = 0; mi < 2; ++mi)
            af[mi] = *(const bf16x8*)&Bs[aoff + mi * 128];
#pragma unroll
        for (int c = 0; c < 3; ++c) {
            bf16x8 bfr[2];
#pragma unroll
            for (int ni = 0; ni < 2; ++ni)
                bfr[ni] = *(const bf16x8*)&As[boff + c * 2048 + ni * 128];
#pragma unroll
            for (int mi = 0; mi < 2; ++mi)
#pragma unroll
                for (int ni = 0; ni < 2; ++ni)
                    acc[c][mi][ni] = __builtin_amdgcn_mfma_f32_16x16x32_bf16(
                        af[mi], bfr[ni], acc[c][mi][ni], 0, 0, 0);
        }
        __syncthreads();
    }
    // all As/Bs reads drained by the final barrier — safe to overlay outs.

    // ---- blend: all 48 mini-MFMAs upfront, results held in registers ----
    bf16x8 wf[2];
#pragma unroll
    for (int ni = 0; ni < 2; ++ni)
        wf[ni] = *(const bf16x8*)&wtsB[(((vtile * 4 + kq) * 64) +
                                        wavev * 32 + ni * 16 + l15) * 8];

    int bframe = ((btile * 4 + kq) * 64 + waveb * 32 + l15) * 8;  // + mi*128

    float res3[2][2][4][3];    // [mi][ni][r][m]
#pragma unroll
    for (int mi = 0; mi < 2; ++mi) {
#pragma unroll
        for (int m = 0; m < 3; ++m) {
            f32x4 T[4][2] = {};
#pragma unroll
            for (int c4 = 0; c4 < 4; ++c4) {
                int mc = m * 4 + c4;
                bf16x8 gf = *(const bf16x8*)&G2B[mc * 32768 + bframe + mi * 128];
#pragma unroll
                for (int ni = 0; ni < 2; ++ni)
                    T[c4][ni] = __builtin_amdgcn_mfma_f32_16x16x32_bf16(
                        gf, wf[ni], T[c4][ni], 0, 0, 0);
            }
#pragma unroll
            for (int ni = 0; ni < 2; ++ni) {
#pragma unroll
                for (int r = 0; r < 4; ++r) {
                    int bl = waveb * 32 + mi * 16 + (kq << 2) + r;
                    int b  = btile * 64 + bl;
                    float x = acc[0][mi][ni][r];
                    float y = acc[1][mi][ni][r];
                    float z = acc[2][mi][ni][r];
                    res3[mi][ni][r][m] = T[3][ni][r] + T[0][ni][r] * x +
                                         T[1][ni][r] * y + T[2][ni][r] * z +
                                         trans[b * 3 + m];
                }
            }
        }
    }

    // ---- 2-pass LDS transpose + sector-dense store ----
    int fvalid = (NV - vtile * 64) * 3;           // floats valid in this span
    if (fvalid > 192) fvalid = 192;
#pragma unroll
    for (int pass = 0; pass < 2; ++pass) {
        if (waveb == pass) {
            // this half's waves own rows pass*32 .. pass*32+31
#pragma unroll
            for (int mi = 0; mi < 2; ++mi) {
#pragma unroll
                for (int ni = 0; ni < 2; ++ni) {
                    int vl = wavev * 32 + ni * 16 + l15;
#pragma unroll
                    for (int r = 0; r < 4; ++r) {
                        int row = mi * 16 + (kq << 2) + r;   // 0..31
#pragma unroll
                        for (int m = 0; m < 3; ++m)
                            outs[row * 204 + vl * 3 + m] = res3[mi][ni][r][m];
                    }
                }
            }
        }
        __syncthreads();
        // readback: one full 768 B row per store instruction (48 lanes x
        // dwordx4); 8 rows per wave.
        if (lane < 48) {
            int fbase = lane * 4;
#pragma unroll
            for (int it = 0; it < 8; ++it) {
                int bl = wid * 8 + it;                       // 0..31
                int b  = btile * 64 + pass * 32 + bl;
                const float* src = &outs[bl * 204 + fbase];
                float* dst = &outp[(size_t)b * V3 + (size_t)vtile * 192 + fbase];
                if (fbase + 4 <= fvalid) {
                    *(f4u*)dst = *(const f4u*)src;
                } else {
#pragma unroll
                    for (int k2 = 0; k2 < 4; ++k2)
                        if (fbase + k2 < fvalid) dst[k2] = src[k2];
                }
            }
        }
        if (pass == 0) __syncthreads();   // protect rows before pass-1 overwrite
    }
}

extern "C" void kernel_launch(void* const* d_in, const int* in_sizes, int n_in,
                              void* d_out, int out_size, void* d_ws, size_t ws_size,
                              hipStream_t stream)
{
    const float* pose   = (const float*)d_in[0];
    const float* betas  = (const float*)d_in[1];
    const float* trans  = (const float*)d_in[2];
    const float* vtempl = (const float*)d_in[3];
    const float* shdirs = (const float*)d_in[4];
    const float* pdirs  = (const float*)d_in[5];
    const float* Jreg   = (const float*)d_in[6];
    const float* wts    = (const float*)d_in[7];
    float* out = (float*)d_out;
    char* ws = (char*)d_ws;

    float* Jc              = (float*)(ws);                      // 792 fl (4 KB)
    __hip_bfloat16* ABsw   = (__hip_bfloat16*)(ws + 4096);      // 229376 bf16
    __hip_bfloat16* G2B    = (__hip_bfloat16*)(ws + 462848);    // 393216 bf16
    __hip_bfloat16* wtsB   = (__hip_bfloat16*)(ws + 1249280);   // 221184 bf16
    __hip_bfloat16* pdBsw  = (__hip_bfloat16*)(ws + 1691648);   // 4644864 bf16

    hipMemsetAsync(Jc, 0, NJ * 33 * sizeof(float), stream);
    hipLaunchKernelGGL(k0, dim3(NJ, 4), dim3(256), 0, stream, Jreg, vtempl, shdirs, Jc);
    hipLaunchKernelGGL(kpack, dim3(2268), dim3(256), 0, stream, pdirs, shdirs, vtempl, pdBsw);
    hipLaunchKernelGGL(kwB, dim3(108), dim3(256), 0, stream, wts, wtsB);
    hipLaunchKernelGGL(k1, dim3(NB / 4), dim3(256), 0, stream,
                       pose, betas, trans, Jc, ABsw, G2B, out);
    hipLaunchKernelGGL(k2g, dim3(108, 16), dim3(256), 0, stream,
                       pdBsw, ABsw, G2B, wtsB, trans, out);
}